// Round 3
// baseline (1278.399 us; speedup 1.0000x reference)
//
#include <hip/hip_runtime.h>
#include <hip/hip_bf16.h>

typedef __attribute__((ext_vector_type(8))) short short8;
typedef __attribute__((ext_vector_type(8))) _Float16 half8;
typedef __attribute__((ext_vector_type(4))) float f32x4;
typedef __attribute__((ext_vector_type(4))) unsigned short ushort4v;
typedef unsigned short us;

#define GLDS16(G, L) __builtin_amdgcn_global_load_lds( \
    (const __attribute__((address_space(1))) void*)(G), \
    (__attribute__((address_space(3))) void*)(L), 16, 0, 0)

__device__ __forceinline__ us f2bf(float x) {
    unsigned int u = __builtin_bit_cast(unsigned int, x);
    u += 0x7fffu + ((u >> 16) & 1u);
    return (us)(u >> 16);
}
__device__ __forceinline__ float bf2f(us h) {
    unsigned int u = ((unsigned int)h) << 16;
    return __builtin_bit_cast(float, u);
}

__global__ void k_sentinel(float* p) {
    if (threadIdx.x == 0 && blockIdx.x == 0) p[0] = 12345.0f;
}

// ---------------- split fp32 -> bf16 hi + bf16 lo ----------------
__global__ void k_split(const float* __restrict__ in, us* __restrict__ hi,
                        us* __restrict__ lo, long n4) {
    long i = (long)blockIdx.x * blockDim.x + threadIdx.x;
    long stride = (long)gridDim.x * blockDim.x;
    for (; i < n4; i += stride) {
        float4 v = ((const float4*)in)[i];
        float vv[4] = {v.x, v.y, v.z, v.w};
        ushort4v h, l;
#pragma unroll
        for (int j = 0; j < 4; j++) {
            us hj = f2bf(vv[j]);
            h[j] = hj;
            l[j] = f2bf(vv[j] - bf2f(hj));
        }
        ((ushort4v*)hi)[i] = h;
        ((ushort4v*)lo)[i] = l;
    }
}

// ---------------- weight transpose+split: f32 [K][N] -> bf16 [N][K] ----------------
template <bool LO>
__global__ void k_wtrans(const float* __restrict__ in, us* __restrict__ hi,
                         us* __restrict__ lo, int K, int N) {
    __shared__ float tile[32][33];
    int n0 = blockIdx.x * 32, k0 = blockIdx.y * 32;
    int tx = threadIdx.x, ty = threadIdx.y;
#pragma unroll
    for (int r = ty; r < 32; r += 8)
        tile[r][tx] = in[(size_t)(k0 + r) * N + n0 + tx];
    __syncthreads();
#pragma unroll
    for (int r = ty; r < 32; r += 8) {
        float x = tile[tx][r];
        size_t o = (size_t)(n0 + r) * K + k0 + tx;
        us h = f2bf(x);
        hi[o] = h;
        if (LO) lo[o] = f2bf(x - bf2f(h));
    }
}

// ---------------- row softmax: 2048 fp32 -> 2048 bf16, one block per row ----------------
__device__ __forceinline__ float wredmax(float v) {
#pragma unroll
    for (int off = 32; off > 0; off >>= 1) v = fmaxf(v, __shfl_xor(v, off, 64));
    return v;
}
__device__ __forceinline__ float wredsum(float v) {
#pragma unroll
    for (int off = 32; off > 0; off >>= 1) v += __shfl_xor(v, off, 64);
    return v;
}

__global__ __launch_bounds__(256) void k_softmax(const float* __restrict__ S,
                                                 us* __restrict__ P) {
    __shared__ float red[8];
    size_t base = (size_t)blockIdx.x * 2048;
    int t = threadIdx.x;
    float4 a = ((const float4*)(S + base))[2 * t];
    float4 b = ((const float4*)(S + base))[2 * t + 1];
    float v[8] = {a.x, a.y, a.z, a.w, b.x, b.y, b.z, b.w};
    float m = v[0];
#pragma unroll
    for (int j = 1; j < 8; j++) m = fmaxf(m, v[j]);
    m = wredmax(m);
    int wv = t >> 6;
    if ((t & 63) == 0) red[wv] = m;
    __syncthreads();
    m = fmaxf(fmaxf(red[0], red[1]), fmaxf(red[2], red[3]));
    float s = 0.f;
#pragma unroll
    for (int j = 0; j < 8; j++) { v[j] = __expf(v[j] - m); s += v[j]; }
    s = wredsum(s);
    if ((t & 63) == 0) red[4 + wv] = s;
    __syncthreads();
    s = red[4] + red[5] + red[6] + red[7];
    float inv = 1.f / s;
    ushort4v o0, o1;
#pragma unroll
    for (int j = 0; j < 4; j++) o0[j] = f2bf(v[j] * inv);
#pragma unroll
    for (int j = 0; j < 4; j++) o1[j] = f2bf(v[4 + j] * inv);
    ((ushort4v*)(P + base))[2 * t] = o0;
    ((ushort4v*)(P + base))[2 * t + 1] = o1;
}

// ---------------- 128-tile GEMM (kept for NPASS=3 + batched/small shapes) ----------------
// NPASS=3: A,B given as hi/lo bf16 pairs, acc = ah*bh + ah*bl + al*bh
// OUT_MODE: 0=f32  1=bf16  2=bf16 split  3=bf16 transposed per 2048-row batch  4=fp16
template <int NPASS, int OUT_MODE, bool GELU_ACT, bool F16IN>
__global__ __launch_bounds__(256, 2) void k_gemm(
    const us* __restrict__ Ahi, const us* __restrict__ Alo,
    const us* __restrict__ Bhi, const us* __restrict__ Blo,
    const float* __restrict__ bias,
    void* __restrict__ C0, void* __restrict__ C1,
    int M, int N, int K, long sA, long sB, long sC) {
    constexpr int NT = (NPASS == 3) ? 4 : 2;
    __shared__ __align__(16) us lds[NT][4096];

    const int tid = threadIdx.x;
    const int wave = tid >> 6, lane = tid & 63;
    const int wr = wave >> 1, wc = wave & 1;
    const int l15 = lane & 15, l4 = lane >> 4;
    const int m0 = blockIdx.x * 128, n0 = blockIdx.y * 128;
    const size_t zA = (size_t)blockIdx.z * sA;
    const size_t zB = (size_t)blockIdx.z * sB;
    const size_t zC = (size_t)blockIdx.z * sC;
    const us* pAh = Ahi + zA;
    const us* pBh = Bhi + zB;
    const us* pAl = (NPASS == 3) ? (Alo + zA) : nullptr;
    const us* pBl = (NPASS == 3) ? (Blo + zB) : nullptr;

    f32x4 acc[4][4] = {};

    auto stage = [&](const us* __restrict__ g, us* l, int r0, int kk) {
#pragma unroll
        for (int i = 0; i < 2; i++) {
            int s = (i << 8) + tid;
            int row = s >> 2;
            int csw = s & 3;
            int chunk = csw ^ ((row >> 1) & 3);
            const us* src = g + (size_t)(r0 + row) * K + kk + chunk * 8;
            us* dst = l + (((i << 8) + (wave << 6)) << 3);
            GLDS16(src, dst);
        }
    };

    for (int kk = 0; kk < K; kk += 32) {
        stage(pAh, lds[0], m0, kk);
        stage(pBh, lds[1], n0, kk);
        if (NPASS == 3) {
            stage(pAl, lds[2], m0, kk);
            stage(pBl, lds[3], n0, kk);
        }
        __syncthreads();

        short8 ah[4], bh[4], al[4], bl[4];
#pragma unroll
        for (int f = 0; f < 4; f++) {
            int ra = (wr << 6) + (f << 4) + l15;
            ah[f] = *(const short8*)(&lds[0][(ra << 5) + ((l4 ^ ((ra >> 1) & 3)) << 3)]);
            int rb = (wc << 6) + (f << 4) + l15;
            bh[f] = *(const short8*)(&lds[1][(rb << 5) + ((l4 ^ ((rb >> 1) & 3)) << 3)]);
            if (NPASS == 3) {
                al[f] = *(const short8*)(&lds[2][(ra << 5) + ((l4 ^ ((ra >> 1) & 3)) << 3)]);
                bl[f] = *(const short8*)(&lds[3][(rb << 5) + ((l4 ^ ((rb >> 1) & 3)) << 3)]);
            }
        }
#pragma unroll
        for (int fm = 0; fm < 4; fm++)
#pragma unroll
            for (int fn = 0; fn < 4; fn++) {
                if (F16IN) {
                    acc[fm][fn] = __builtin_amdgcn_mfma_f32_16x16x32_f16(
                        __builtin_bit_cast(half8, ah[fm]), __builtin_bit_cast(half8, bh[fn]),
                        acc[fm][fn], 0, 0, 0);
                } else {
                    acc[fm][fn] = __builtin_amdgcn_mfma_f32_16x16x32_bf16(ah[fm], bh[fn], acc[fm][fn], 0, 0, 0);
                    if (NPASS == 3) {
                        acc[fm][fn] = __builtin_amdgcn_mfma_f32_16x16x32_bf16(ah[fm], bl[fn], acc[fm][fn], 0, 0, 0);
                        acc[fm][fn] = __builtin_amdgcn_mfma_f32_16x16x32_bf16(al[fm], bh[fn], acc[fm][fn], 0, 0, 0);
                    }
                }
            }
        __syncthreads();
    }

    float bv[4];
#pragma unroll
    for (int fn = 0; fn < 4; fn++)
        bv[fn] = bias ? bias[n0 + (wc << 6) + (fn << 4) + l15] : 0.f;

#pragma unroll
    for (int fm = 0; fm < 4; fm++) {
        int rbase = m0 + (wr << 6) + (fm << 4) + (l4 << 2);
#pragma unroll
        for (int fn = 0; fn < 4; fn++) {
            int col = n0 + (wc << 6) + (fn << 4) + l15;
#pragma unroll
            for (int r = 0; r < 4; r++) {
                float x = acc[fm][fn][r] + bv[fn];
                if (GELU_ACT) x = 0.5f * x * (1.f + erff(x * 0.70710678118654752f));
                size_t row = (size_t)(rbase + r);
                if (OUT_MODE == 3) {
                    size_t o = ((row >> 11) * (size_t)N + (size_t)col) * 2048 + (row & 2047);
                    ((us*)C0)[o] = f2bf(x);
                } else {
                    size_t o = zC + row * N + col;
                    if (OUT_MODE == 0) {
                        ((float*)C0)[o] = x;
                    } else if (OUT_MODE == 1) {
                        ((us*)C0)[o] = f2bf(x);
                    } else if (OUT_MODE == 2) {
                        us h = f2bf(x);
                        ((us*)C0)[o] = h;
                        ((us*)C1)[o] = f2bf(x - bf2f(h));
                    } else if (OUT_MODE == 4) {
                        ((_Float16*)C0)[o] = (_Float16)x;
                    }
                }
            }
        }
    }
    (void)M;
}

// ---------------- 256-tile pipelined GEMM (NPASS=1): C = act(A[M][K] * B[N][K]^T + bias) ----
// 8 waves (2M x 4N), per-wave 128x64 out, BK=32, 4-slot LDS ring (128 KiB),
// prefetch 3 tiles ahead, counted vmcnt (8 steady / 4 / 0 drain), setprio around MFMA.
// OUT_MODE: 0=f32  1=bf16  3=bf16 transposed per 2048-row batch
template <int OUT_MODE, bool GELU_ACT>
__global__ __launch_bounds__(512, 2) void k_gemm256(
    const us* __restrict__ A, const us* __restrict__ B,
    const float* __restrict__ bias, void* __restrict__ C,
    int M, int N, int K) {
    __shared__ __align__(16) us ldsA[4][8192];
    __shared__ __align__(16) us ldsB[4][8192];

    const int tid = threadIdx.x;
    const int wave = tid >> 6, lane = tid & 63;
    const int wr = wave >> 2, wc = wave & 3;   // 2 x 4 wave grid
    const int l15 = lane & 15, l4 = lane >> 4;
    const int m0 = blockIdx.x * 256, n0 = blockIdx.y * 256;
    const int NT = K >> 5;

    f32x4 acc[8][4] = {};

    // tile-invariant fragment offsets (us units) within a slot; swizzle chunk^=(row>>1)&3
    int aoff[8], boff[4];
#pragma unroll
    for (int f = 0; f < 8; ++f) {
        int r = (wr << 7) + (f << 4) + l15;
        aoff[f] = (r << 5) + ((l4 ^ ((r >> 1) & 3)) << 3);
    }
#pragma unroll
    for (int f = 0; f < 4; ++f) {
        int r = (wc << 6) + (f << 4) + l15;
        boff[f] = (r << 5) + ((l4 ^ ((r >> 1) & 3)) << 3);
    }

    // stage one 256x32 tile (16 KiB): 1024 slots of 16B; LDS linear, source pre-swizzled
    auto stage = [&](const us* __restrict__ g, us* l, int r0, int kk) {
#pragma unroll
        for (int i = 0; i < 2; ++i) {
            int s = (i << 9) + tid;
            int row = s >> 2;
            int c = (s & 3) ^ ((row >> 1) & 3);
            const us* src = g + (size_t)(r0 + row) * K + kk + (c << 3);
            us* dst = l + (((i << 9) + (wave << 6)) << 3);  // wave-uniform base + lane*16B
            GLDS16(src, dst);
        }
    };

    // prologue: tiles 0,1,2 in flight; require tile 0 complete (allow 8 = tiles 1,2)
    stage(A, ldsA[0], m0, 0);  stage(B, ldsB[0], n0, 0);
    stage(A, ldsA[1], m0, 32); stage(B, ldsB[1], n0, 32);
    stage(A, ldsA[2], m0, 64); stage(B, ldsB[2], n0, 64);
    asm volatile("s_waitcnt vmcnt(8)" ::: "memory");
    __builtin_amdgcn_s_barrier();
    __builtin_amdgcn_sched_barrier(0);

    for (int t = 0; t < NT; ++t) {
        if (t + 3 < NT) {  // stage tile t+3 into slot (t+3)&3 (readers done at barrier end of t-1)
            int kk = (t + 3) << 5, sl = (t + 3) & 3;
            stage(A, ldsA[sl], m0, kk);
            stage(B, ldsB[sl], n0, kk);
        }
        const us* la = ldsA[t & 3];
        const us* lb = ldsB[t & 3];
        short8 af[8], bfr[4];
#pragma unroll
        for (int f = 0; f < 8; ++f) af[f] = *(const short8*)(la + aoff[f]);
#pragma unroll
        for (int f = 0; f < 2; ++f) bfr[f] = *(const short8*)(lb + boff[f]);
        __builtin_amdgcn_s_setprio(1);
#pragma unroll
        for (int fm = 0; fm < 8; ++fm)
#pragma unroll
            for (int fn = 0; fn < 2; ++fn)
                acc[fm][fn] = __builtin_amdgcn_mfma_f32_16x16x32_bf16(af[fm], bfr[fn], acc[fm][fn], 0, 0, 0);
        __builtin_amdgcn_s_setprio(0);
#pragma unroll
        for (int f = 2; f < 4; ++f) bfr[f] = *(const short8*)(lb + boff[f]);
        __builtin_amdgcn_s_setprio(1);
#pragma unroll
        for (int fm = 0; fm < 8; ++fm)
#pragma unroll
            for (int fn = 2; fn < 4; ++fn)
                acc[fm][fn] = __builtin_amdgcn_mfma_f32_16x16x32_bf16(af[fm], bfr[fn], acc[fm][fn], 0, 0, 0);
        __builtin_amdgcn_s_setprio(0);

        if (t + 1 < NT) {  // require stage(t+1) complete; allow t+2,t+3 in flight
            if (t + 3 < NT)      asm volatile("s_waitcnt vmcnt(8)" ::: "memory");
            else if (t + 2 < NT) asm volatile("s_waitcnt vmcnt(4)" ::: "memory");
            else                 asm volatile("s_waitcnt vmcnt(0)" ::: "memory");
            __builtin_amdgcn_s_barrier();
            __builtin_amdgcn_sched_barrier(0);
        }
    }

    float bv[4];
#pragma unroll
    for (int fn = 0; fn < 4; ++fn)
        bv[fn] = bias ? bias[n0 + (wc << 6) + (fn << 4) + l15] : 0.f;
#pragma unroll
    for (int fm = 0; fm < 8; ++fm) {
        int rbase = m0 + (wr << 7) + (fm << 4) + (l4 << 2);
#pragma unroll
        for (int fn = 0; fn < 4; ++fn) {
            int col = n0 + (wc << 6) + (fn << 4) + l15;
#pragma unroll
            for (int r = 0; r < 4; ++r) {
                float x = acc[fm][fn][r] + bv[fn];
                if (GELU_ACT) x = 0.5f * x * (1.f + erff(x * 0.70710678118654752f));
                size_t row = (size_t)(rbase + r);
                if (OUT_MODE == 3) {
                    size_t o = ((row >> 11) * (size_t)N + (size_t)col) * 2048 + (row & 2047);
                    ((us*)C)[o] = f2bf(x);
                } else {
                    size_t o = row * (size_t)N + col;
                    if (OUT_MODE == 0) ((float*)C)[o] = x;
                    else               ((us*)C)[o] = f2bf(x);
                }
            }
        }
    }
    (void)M;
}

extern "C" void kernel_launch(void* const* d_in, const int* in_sizes, int n_in,
                              void* d_out, int out_size, void* d_ws, size_t ws_size,
                              hipStream_t stream) {
    (void)in_sizes; (void)n_in; (void)out_size;
    const float* g_q   = (const float*)d_in[0];
    const float* g_kv  = (const float*)d_in[1];
    const float* g_Wkv = (const float*)d_in[2];
    const float* g_bkv = (const float*)d_in[3];
    const float* g_Wq  = (const float*)d_in[4];
    const float* g_bq  = (const float*)d_in[5];
    const float* g_W1  = (const float*)d_in[6];
    const float* g_b1  = (const float*)d_in[7];
    const float* g_W2  = (const float*)d_in[8];
    const float* g_b2  = (const float*)d_in[9];

    const size_t R = 33554432ull;     // 32 MiB: one [16384][1024] bf16 activation
    const size_t NHt = 16777216ull;
    const size_t WREG = 16777216ull;
    const long SH = 2048L * 1024;
    const long SS = 2048L * 2048;
    char* ws = (char*)d_ws;
    dim3 tb32(32, 8);

    const size_t need_A = 5 * R + WREG;  // 176 MiB
    const size_t need_B = 4 * R + WREG;  // 144 MiB
    const size_t need_C = 3 * R + WREG;  // 112 MiB

    if (ws_size >= need_A) {
        // ---- Plan A: 2-batch chunks, scores/P/q-frag in d_out ----
        us* qsh = (us*)ws;
        us* khi = (us*)(ws + R);
        us* klo = (us*)(ws + 2 * R);
        us* vT  = (us*)(ws + 3 * R);
        us* qsl = (us*)(ws + 4 * R);
        char* wreg = ws + 5 * R;
        us* wkvThi = (us*)wreg;
        us* wkvTlo = (us*)(wreg + 4194304);
        us* wqThi  = (us*)(wreg + 8388608);
        us* wqTlo  = (us*)(wreg + 10485760);
        us* w1T    = (us*)wreg;             // overlays wkvT (dead by MLP)
        us* w2T    = (us*)(wreg + 8388608); // overlays wqT  (dead by MLP)
        us* cvh = (us*)d_out;
        us* cvl = cvh + NHt;
        float* scores_c = (float*)d_out;
        us* P_c  = (us*)((char*)d_out + 33554432);
        us* qh_c = (us*)((char*)d_out + 50331648);
        us* ql_c = (us*)((char*)d_out + 58720256);

        k_wtrans<true><<<dim3(64, 32), tb32, 0, stream>>>(g_Wkv, wkvThi, wkvTlo, 1024, 2048);
        k_wtrans<true><<<dim3(32, 32), tb32, 0, stream>>>(g_Wq, wqThi, wqTlo, 1024, 1024);
        k_split<<<4096, 256, 0, stream>>>(g_kv, cvh, cvl, 4194304);
        k_gemm<3, 2, false, false><<<dim3(128, 8, 1), 256, 0, stream>>>(
            cvh, cvl, wkvThi, wkvTlo, g_bkv, khi, klo, 16384, 1024, 1024, 0, 0, 0);
        k_gemm256<3, false><<<dim3(64, 4), 512, 0, stream>>>(
            cvh, wkvThi + 1048576, g_bkv + 1024, vT, 16384, 1024, 1024);
        k_split<<<4096, 256, 0, stream>>>(g_q, qsh, qsl, 4194304);
        for (int c = 0; c < 4; ++c) {
            size_t ro = (size_t)c * 4096 * 1024;
            k_gemm<3, 2, false, false><<<dim3(32, 8, 1), 256, 0, stream>>>(
                qsh + ro, qsl + ro, wqThi, wqTlo, g_bq, qh_c, ql_c, 4096, 1024, 1024, 0, 0, 0);
            k_gemm<3, 0, false, false><<<dim3(16, 16, 2), 256, 0, stream>>>(
                qh_c, ql_c, khi + ro, klo + ro, nullptr, scores_c, nullptr,
                2048, 2048, 1024, SH, SH, SS);
            k_softmax<<<4096, 256, 0, stream>>>(scores_c, P_c);
            k_gemm<1, 1, false, false><<<dim3(16, 8, 2), 256, 0, stream>>>(
                P_c, nullptr, vT + ro, nullptr, nullptr, qsh + ro, nullptr,
                2048, 1024, 2048, SS, SH, SH);
        }
        k_wtrans<false><<<dim3(128, 32), tb32, 0, stream>>>(g_W1, w1T, nullptr, 1024, 4096);
        k_wtrans<false><<<dim3(32, 128), tb32, 0, stream>>>(g_W2, w2T, nullptr, 4096, 1024);
        us* hidden = khi;  // overlays khi..qsl (134 MiB exact)
        k_gemm256<1, true><<<dim3(64, 16), 512, 0, stream>>>(
            qsh, w1T, g_b1, hidden, 16384, 4096, 1024);
        k_gemm256<0, false><<<dim3(64, 4), 512, 0, stream>>>(
            hidden, w2T, g_b2, d_out, 16384, 1024, 4096);
    } else if (ws_size >= need_B) {
        // ---- Plan B: 1-batch chunks, q split stays in d_out ----
        us* khi = (us*)ws;
        us* klo = (us*)(ws + R);
        us* vT  = (us*)(ws + 2 * R);
        char* sc = ws + 3 * R;
        float* scores_c = (float*)sc;
        us* P_c  = (us*)(sc + 16777216);
        us* qh_c = (us*)(sc + 25165824);
        us* ql_c = (us*)(sc + 29360128);
        char* wreg = ws + 4 * R;
        us* wkvThi = (us*)wreg;
        us* wkvTlo = (us*)(wreg + 4194304);
        us* wqThi  = (us*)(wreg + 8388608);
        us* wqTlo  = (us*)(wreg + 10485760);
        us* w1T    = (us*)wreg;
        us* w2T    = (us*)(wreg + 8388608);
        us* cvh = (us*)d_out;
        us* cvl = cvh + NHt;

        k_wtrans<true><<<dim3(64, 32), tb32, 0, stream>>>(g_Wkv, wkvThi, wkvTlo, 1024, 2048);
        k_wtrans<true><<<dim3(32, 32), tb32, 0, stream>>>(g_Wq, wqThi, wqTlo, 1024, 1024);
        k_split<<<4096, 256, 0, stream>>>(g_kv, cvh, cvl, 4194304);
        k_gemm<3, 2, false, false><<<dim3(128, 8, 1), 256, 0, stream>>>(
            cvh, cvl, wkvThi, wkvTlo, g_bkv, khi, klo, 16384, 1024, 1024, 0, 0, 0);
        k_gemm<1, 3, false, false><<<dim3(128, 8, 1), 256, 0, stream>>>(
            cvh, nullptr, wkvThi + 1048576, nullptr, g_bkv + 1024, vT, nullptr,
            16384, 1024, 1024, 0, 0, 0);
        k_split<<<4096, 256, 0, stream>>>(g_q, cvh, cvl, 4194304);
        for (int c = 0; c < 8; ++c) {
            size_t ro = (size_t)c * 2048 * 1024;
            k_gemm<3, 2, false, false><<<dim3(16, 8, 1), 256, 0, stream>>>(
                cvh + ro, cvl + ro, wqThi, wqTlo, g_bq, qh_c, ql_c, 2048, 1024, 1024, 0, 0, 0);
            k_gemm<3, 0, false, false><<<dim3(16, 16, 1), 256, 0, stream>>>(
                qh_c, ql_c, khi + ro, klo + ro, nullptr, scores_c, nullptr,
                2048, 2048, 1024, 0, 0, 0);
            k_softmax<<<2048, 256, 0, stream>>>(scores_c, P_c);
            k_gemm<1, 1, false, false><<<dim3(16, 8, 1), 256, 0, stream>>>(
                P_c, nullptr, vT + ro, nullptr, nullptr, cvh + ro, nullptr,
                2048, 1024, 2048, 0, 0, 0);
        }
        k_wtrans<false><<<dim3(128, 32), tb32, 0, stream>>>(g_W1, w1T, nullptr, 1024, 4096);
        k_wtrans<false><<<dim3(32, 128), tb32, 0, stream>>>(g_W2, w2T, nullptr, 4096, 1024);
        us* hidden = khi;
        k_gemm<1, 1, true, false><<<dim3(128, 32, 1), 256, 0, stream>>>(
            (us*)d_out, nullptr, w1T, nullptr, g_b1, hidden, nullptr, 16384, 4096, 1024, 0, 0, 0);
        k_gemm<1, 0, false, false><<<dim3(128, 8, 1), 256, 0, stream>>>(
            hidden, nullptr, w2T, nullptr, g_b2, d_out, nullptr, 16384, 1024, 4096, 0, 0, 0);
    } else if (ws_size >= need_C) {
        // ---- Plan C: fp16 q/k single-pass scores (lower precision fallback) ----
        us* khF = (us*)ws;
        us* vT  = (us*)(ws + R);
        char* sc = ws + 2 * R;
        float* scores_c = (float*)sc;
        us* P_c  = (us*)(sc + 16777216);
        us* qF_c = (us*)(sc + 25165824);
        char* wreg = ws + 3 * R;
        us* wkvThi = (us*)wreg;
        us* wkvTlo = (us*)(wreg + 4194304);
        us* wqThi  = (us*)(wreg + 8388608);
        us* wqTlo  = (us*)(wreg + 10485760);
        us* w1T    = (us*)wreg;
        us* w2T    = (us*)(wreg + 8388608);
        us* cvh = (us*)d_out;
        us* cvl = cvh + NHt;

        k_wtrans<true><<<dim3(64, 32), tb32, 0, stream>>>(g_Wkv, wkvThi, wkvTlo, 1024, 2048);
        k_wtrans<true><<<dim3(32, 32), tb32, 0, stream>>>(g_Wq, wqThi, wqTlo, 1024, 1024);
        k_split<<<4096, 256, 0, stream>>>(g_kv, cvh, cvl, 4194304);
        k_gemm<3, 4, false, false><<<dim3(128, 8, 1), 256, 0, stream>>>(
            cvh, cvl, wkvThi, wkvTlo, g_bkv, khF, nullptr, 16384, 1024, 1024, 0, 0, 0);
        k_gemm<1, 3, false, false><<<dim3(128, 8, 1), 256, 0, stream>>>(
            cvh, nullptr, wkvThi + 1048576, nullptr, g_bkv + 1024, vT, nullptr,
            16384, 1024, 1024, 0, 0, 0);
        k_split<<<4096, 256, 0, stream>>>(g_q, cvh, cvl, 4194304);
        for (int c = 0; c < 8; ++c) {
            size_t ro = (size_t)c * 2048 * 1024;
            k_gemm<3, 4, false, false><<<dim3(16, 8, 1), 256, 0, stream>>>(
                cvh + ro, cvl + ro, wqThi, wqTlo, g_bq, qF_c, nullptr, 2048, 1024, 1024, 0, 0, 0);
            k_gemm<1, 0, false, true><<<dim3(16, 16, 1), 256, 0, stream>>>(
                qF_c, nullptr, khF + ro, nullptr, nullptr, scores_c, nullptr,
                2048, 2048, 1024, 0, 0, 0);
            k_softmax<<<2048, 256, 0, stream>>>(scores_c, P_c);
            k_gemm<1, 1, false, false><<<dim3(16, 8, 1), 256, 0, stream>>>(
                P_c, nullptr, vT + ro, nullptr, nullptr, cvh + ro, nullptr,
                2048, 1024, 2048, 0, 0, 0);
        }
        k_wtrans<false><<<dim3(128, 32), tb32, 0, stream>>>(g_W1, w1T, nullptr, 1024, 4096);
        k_wtrans<false><<<dim3(32, 128), tb32, 0, stream>>>(g_W2, w2T, nullptr, 4096, 1024);
        for (int h = 1; h >= 0; --h) {
            us* hidden_c = khF;
            k_gemm<1, 1, true, false><<<dim3(64, 32, 1), 256, 0, stream>>>(
                (us*)d_out + (size_t)h * 8192 * 1024, nullptr, w1T, nullptr, g_b1,
                hidden_c, nullptr, 8192, 4096, 1024, 0, 0, 0);
            k_gemm<1, 0, false, false><<<dim3(64, 8, 1), 256, 0, stream>>>(
                hidden_c, nullptr, w2T, nullptr, g_b2,
                (float*)d_out + (size_t)h * 8192 * 1024, nullptr, 8192, 1024, 4096, 0, 0, 0);
        }
    } else {
        k_sentinel<<<1, 64, 0, stream>>>((float*)d_out);
    }
}

// Round 4
// 937.778 us; speedup vs baseline: 1.3632x; 1.3632x over previous
//
#include <hip/hip_runtime.h>
#include <hip/hip_bf16.h>

typedef __attribute__((ext_vector_type(8))) short short8;
typedef __attribute__((ext_vector_type(8))) _Float16 half8;
typedef __attribute__((ext_vector_type(4))) _Float16 half4v;
typedef __attribute__((ext_vector_type(4))) float f32x4;
typedef unsigned short us;

#define GLDS16(G, L) __builtin_amdgcn_global_load_lds( \
    (const __attribute__((address_space(1))) void*)(G), \
    (__attribute__((address_space(3))) void*)(L), 16, 0, 0)

__global__ void k_sentinel(float* p) {
    if (threadIdx.x == 0 && blockIdx.x == 0) p[0] = 12345.0f;
}

// ---------------- cast fp32 -> fp16 ----------------
__global__ void k_cast(const float* __restrict__ in, _Float16* __restrict__ out, long n4) {
    long i = (long)blockIdx.x * blockDim.x + threadIdx.x;
    long stride = (long)gridDim.x * blockDim.x;
    for (; i < n4; i += stride) {
        float4 v = ((const float4*)in)[i];
        half4v h;
        h[0] = (_Float16)v.x; h[1] = (_Float16)v.y;
        h[2] = (_Float16)v.z; h[3] = (_Float16)v.w;
        ((half4v*)out)[i] = h;
    }
}

// ---------------- weight transpose+cast: f32 [K][N] -> fp16 [N][K] ----------------
__global__ void k_wtransh(const float* __restrict__ in, _Float16* __restrict__ out,
                          int K, int N) {
    __shared__ float tile[32][33];
    int n0 = blockIdx.x * 32, k0 = blockIdx.y * 32;
    int tx = threadIdx.x, ty = threadIdx.y;
#pragma unroll
    for (int r = ty; r < 32; r += 8)
        tile[r][tx] = in[(size_t)(k0 + r) * N + n0 + tx];
    __syncthreads();
#pragma unroll
    for (int r = ty; r < 32; r += 8)
        out[(size_t)(n0 + r) * K + k0 + tx] = (_Float16)tile[tx][r];
}

// ---------------- row softmax: 2048 fp32 -> 2048 fp16, one block per row ----------------
__device__ __forceinline__ float wredmax(float v) {
#pragma unroll
    for (int off = 32; off > 0; off >>= 1) v = fmaxf(v, __shfl_xor(v, off, 64));
    return v;
}
__device__ __forceinline__ float wredsum(float v) {
#pragma unroll
    for (int off = 32; off > 0; off >>= 1) v += __shfl_xor(v, off, 64);
    return v;
}

__global__ __launch_bounds__(256) void k_softmax(const float* __restrict__ S,
                                                 _Float16* __restrict__ P) {
    __shared__ float red[8];
    size_t base = (size_t)blockIdx.x * 2048;
    int t = threadIdx.x;
    float4 a = ((const float4*)(S + base))[2 * t];
    float4 b = ((const float4*)(S + base))[2 * t + 1];
    float v[8] = {a.x, a.y, a.z, a.w, b.x, b.y, b.z, b.w};
    float m = v[0];
#pragma unroll
    for (int j = 1; j < 8; j++) m = fmaxf(m, v[j]);
    m = wredmax(m);
    int wv = t >> 6;
    if ((t & 63) == 0) red[wv] = m;
    __syncthreads();
    m = fmaxf(fmaxf(red[0], red[1]), fmaxf(red[2], red[3]));
    float s = 0.f;
#pragma unroll
    for (int j = 0; j < 8; j++) { v[j] = __expf(v[j] - m); s += v[j]; }
    s = wredsum(s);
    if ((t & 63) == 0) red[4 + wv] = s;
    __syncthreads();
    s = red[4] + red[5] + red[6] + red[7];
    float inv = 1.f / s;
    half4v o0, o1;
#pragma unroll
    for (int j = 0; j < 4; j++) o0[j] = (_Float16)(v[j] * inv);
#pragma unroll
    for (int j = 0; j < 4; j++) o1[j] = (_Float16)(v[4 + j] * inv);
    ((half4v*)(P + base))[2 * t] = o0;
    ((half4v*)(P + base))[2 * t + 1] = o1;
}

// ---------------- 128-tile fp16 GEMM: C[M][N] = act(A[M][K] * B[N][K]^T + bias) -------
// Proven m97-structure: 4 waves, 64x64/wave, BK=32, global_load_lds w=16,
// source-pre-swizzled LDS (2-way free), mfma_f32_16x16x32_f16.
// OUT_MODE: 0=f32  4=fp16  5=fp16 transposed per 2048-row batch
template <int OUT_MODE, bool GELU_ACT>
__global__ __launch_bounds__(256, 2) void k_gemmh(
    const us* __restrict__ A, const us* __restrict__ B,
    const float* __restrict__ bias, void* __restrict__ C,
    int N, int K, long sA, long sB, long sC) {
    __shared__ __align__(16) us lds[2][4096];  // 0=A tile, 1=B tile (128x32 fp16)

    const int tid = threadIdx.x;
    const int wave = tid >> 6, lane = tid & 63;
    const int wr = wave >> 1, wc = wave & 1;
    const int l15 = lane & 15, l4 = lane >> 4;
    const int m0 = blockIdx.x * 128, n0 = blockIdx.y * 128;
    const us* pA = A + (size_t)blockIdx.z * sA;
    const us* pB = B + (size_t)blockIdx.z * sB;
    const size_t zC = (size_t)blockIdx.z * sC;

    f32x4 acc[4][4] = {};

    // stage 128x32 fp16 tile; LDS dest linear, XOR-swizzle on the GLOBAL source (rule #21)
    auto stage = [&](const us* __restrict__ g, us* l, int r0, int kk) {
#pragma unroll
        for (int i = 0; i < 2; i++) {
            int s = (i << 8) + tid;            // slot 0..511, 16B each
            int row = s >> 2;
            int chunk = (s & 3) ^ ((row >> 1) & 3);
            const us* src = g + (size_t)(r0 + row) * K + kk + chunk * 8;
            us* dst = l + (((i << 8) + (wave << 6)) << 3);  // wave-uniform base
            GLDS16(src, dst);
        }
    };

    for (int kk = 0; kk < K; kk += 32) {
        stage(pA, lds[0], m0, kk);
        stage(pB, lds[1], n0, kk);
        __syncthreads();

        short8 af[4], bf[4];
#pragma unroll
        for (int f = 0; f < 4; f++) {
            int ra = (wr << 6) + (f << 4) + l15;
            af[f] = *(const short8*)(&lds[0][(ra << 5) + ((l4 ^ ((ra >> 1) & 3)) << 3)]);
            int rb = (wc << 6) + (f << 4) + l15;
            bf[f] = *(const short8*)(&lds[1][(rb << 5) + ((l4 ^ ((rb >> 1) & 3)) << 3)]);
        }
#pragma unroll
        for (int fm = 0; fm < 4; fm++)
#pragma unroll
            for (int fn = 0; fn < 4; fn++)
                acc[fm][fn] = __builtin_amdgcn_mfma_f32_16x16x32_f16(
                    __builtin_bit_cast(half8, af[fm]), __builtin_bit_cast(half8, bf[fn]),
                    acc[fm][fn], 0, 0, 0);
        __syncthreads();
    }

    // epilogue: C/D layout col=lane&15, row=(lane>>4)*4+reg [m89-verified, dtype-indep]
    float bv[4];
#pragma unroll
    for (int fn = 0; fn < 4; fn++)
        bv[fn] = bias ? bias[n0 + (wc << 6) + (fn << 4) + l15] : 0.f;

#pragma unroll
    for (int fm = 0; fm < 4; fm++) {
        int rbase = m0 + (wr << 6) + (fm << 4) + (l4 << 2);
#pragma unroll
        for (int fn = 0; fn < 4; fn++) {
            int col = n0 + (wc << 6) + (fn << 4) + l15;
#pragma unroll
            for (int r = 0; r < 4; r++) {
                float x = acc[fm][fn][r] + bv[fn];
                if (GELU_ACT) x = 0.5f * x * (1.f + erff(x * 0.70710678118654752f));
                size_t row = (size_t)(rbase + r);
                if (OUT_MODE == 5) {
                    size_t o = ((row >> 11) * (size_t)N + (size_t)col) * 2048 + (row & 2047);
                    ((_Float16*)C)[o] = (_Float16)x;
                } else {
                    size_t o = zC + row * N + col;
                    if (OUT_MODE == 0) ((float*)C)[o] = x;
                    else               ((_Float16*)C)[o] = (_Float16)x;
                }
            }
        }
    }
}

extern "C" void kernel_launch(void* const* d_in, const int* in_sizes, int n_in,
                              void* d_out, int out_size, void* d_ws, size_t ws_size,
                              hipStream_t stream) {
    (void)in_sizes; (void)n_in; (void)out_size;
    const float* g_q   = (const float*)d_in[0];
    const float* g_kv  = (const float*)d_in[1];
    const float* g_Wkv = (const float*)d_in[2];
    const float* g_bkv = (const float*)d_in[3];
    const float* g_Wq  = (const float*)d_in[4];
    const float* g_bq  = (const float*)d_in[5];
    const float* g_W1  = (const float*)d_in[6];
    const float* g_b1  = (const float*)d_in[7];
    const float* g_W2  = (const float*)d_in[8];
    const float* g_b2  = (const float*)d_in[9];

    const size_t MiB = 1048576ull;
    const long SH = 2048L * 1024;   // per-batch activation elements
    const long SS = 2048L * 2048;   // per-batch score elements
    char* ws = (char*)d_ws;
    dim3 tb32(32, 8);

    if (ws_size < 176 * MiB) {  // proven available in rounds 2-3; guard anyway
        k_sentinel<<<1, 64, 0, stream>>>((float*)d_out);
        return;
    }

    // ---- workspace layout (exactly 176 MiB) ----
    // [xq 32MiB][BIG 128MiB: attn-phase {xkv,k,vT}, MLP-phase hidden][wreg 16MiB]
    _Float16* xq  = (_Float16*)ws;
    char*     BIG = ws + 32 * MiB;
    _Float16* xkv = (_Float16*)BIG;
    _Float16* kf  = (_Float16*)(BIG + 33554432);
    _Float16* vT  = (_Float16*)(BIG + 67108864);
    _Float16* hidden = (_Float16*)BIG;            // 16384x4096 fp16 = 128 MiB exact
    char* wreg = ws + 160 * MiB;
    _Float16* WkvT = (_Float16*)wreg;             // 2048x1024 fp16 = 4 MiB
    _Float16* WqT  = (_Float16*)(wreg + 4194304); // 1024x1024 fp16 = 2 MiB
    _Float16* W1T  = (_Float16*)wreg;             // 4096x1024 fp16 = 8 MiB (after proj dead)
    _Float16* W2T  = (_Float16*)(wreg + 8388608); // 1024x4096 fp16 = 8 MiB

    // d_out doubles as chunk scratch: [scores f32 32MiB][P f16 16MiB][q_c f16 8MiB]
    float*    scores_c = (float*)d_out;
    _Float16* P_c  = (_Float16*)((char*)d_out + 33554432);
    _Float16* q_c  = (_Float16*)((char*)d_out + 50331648);

    // ---- weights + input casts ----
    k_wtransh<<<dim3(64, 32), tb32, 0, stream>>>(g_Wkv, WkvT, 1024, 2048);
    k_wtransh<<<dim3(32, 32), tb32, 0, stream>>>(g_Wq, WqT, 1024, 1024);
    k_cast<<<4096, 256, 0, stream>>>(g_kv, xkv, 4194304);
    k_cast<<<4096, 256, 0, stream>>>(g_q, xq, 4194304);

    // ---- projections (fp16 single-pass) ----
    k_gemmh<4, false><<<dim3(128, 8, 1), 256, 0, stream>>>(
        (const us*)xkv, (const us*)WkvT, g_bkv, kf, 1024, 1024, 0, 0, 0);
    k_gemmh<5, false><<<dim3(128, 8, 1), 256, 0, stream>>>(
        (const us*)xkv, (const us*)(WkvT + (size_t)1024 * 1024), g_bkv + 1024, vT,
        1024, 1024, 0, 0, 0);

    // ---- attention, 4 chunks of 2 batches; scores/P/q_c live in d_out ----
    for (int c = 0; c < 4; ++c) {
        size_t ro = (size_t)c * 4096 * 1024;
        k_gemmh<4, false><<<dim3(32, 8, 1), 256, 0, stream>>>(
            (const us*)(xq + ro), (const us*)WqT, g_bq, q_c, 1024, 1024, 0, 0, 0);
        k_gemmh<0, false><<<dim3(16, 16, 2), 256, 0, stream>>>(
            (const us*)q_c, (const us*)(kf + ro), nullptr, scores_c,
            2048, 1024, SH, SH, SS);
        k_softmax<<<4096, 256, 0, stream>>>(scores_c, P_c);
        k_gemmh<4, false><<<dim3(16, 8, 2), 256, 0, stream>>>(
            (const us*)P_c, (const us*)(vT + ro), nullptr, xq + ro,
            1024, 2048, SS, SH, SH);
    }

    // ---- MLP (fp16), hidden occupies BIG exactly ----
    k_wtransh<<<dim3(128, 32), tb32, 0, stream>>>(g_W1, W1T, 1024, 4096);
    k_wtransh<<<dim3(32, 128), tb32, 0, stream>>>(g_W2, W2T, 4096, 1024);
    k_gemmh<4, true><<<dim3(128, 32, 1), 256, 0, stream>>>(
        (const us*)xq, (const us*)W1T, g_b1, hidden, 4096, 1024, 0, 0, 0);
    k_gemmh<0, false><<<dim3(128, 8, 1), 256, 0, stream>>>(
        (const us*)hidden, (const us*)W2T, g_b2, d_out, 1024, 4096, 0, 0, 0);
}

// Round 5
// 913.920 us; speedup vs baseline: 1.3988x; 1.0261x over previous
//
#include <hip/hip_runtime.h>
#include <hip/hip_bf16.h>

typedef __attribute__((ext_vector_type(8))) short short8;
typedef __attribute__((ext_vector_type(8))) _Float16 half8;
typedef __attribute__((ext_vector_type(4))) _Float16 half4v;
typedef __attribute__((ext_vector_type(4))) float f32x4;
typedef unsigned short us;

#define GLDS16(G, L) __builtin_amdgcn_global_load_lds( \
    (const __attribute__((address_space(1))) void*)(G), \
    (__attribute__((address_space(3))) void*)(L), 16, 0, 0)

__global__ void k_sentinel(float* p) {
    if (threadIdx.x == 0 && blockIdx.x == 0) p[0] = 12345.0f;
}

// ---------------- cast fp32 -> fp16 ----------------
__global__ void k_cast(const float* __restrict__ in, _Float16* __restrict__ out, long n4) {
    long i = (long)blockIdx.x * blockDim.x + threadIdx.x;
    long stride = (long)gridDim.x * blockDim.x;
    for (; i < n4; i += stride) {
        float4 v = ((const float4*)in)[i];
        half4v h;
        h[0] = (_Float16)v.x; h[1] = (_Float16)v.y;
        h[2] = (_Float16)v.z; h[3] = (_Float16)v.w;
        ((half4v*)out)[i] = h;
    }
}

// ---------------- weight transpose+cast: f32 [K][N] -> fp16 [N][K] ----------------
__global__ void k_wtransh(const float* __restrict__ in, _Float16* __restrict__ out,
                          int K, int N) {
    __shared__ float tile[32][33];
    int n0 = blockIdx.x * 32, k0 = blockIdx.y * 32;
    int tx = threadIdx.x, ty = threadIdx.y;
#pragma unroll
    for (int r = ty; r < 32; r += 8)
        tile[r][tx] = in[(size_t)(k0 + r) * N + n0 + tx];
    __syncthreads();
#pragma unroll
    for (int r = ty; r < 32; r += 8)
        out[(size_t)(n0 + r) * K + k0 + tx] = (_Float16)tile[tx][r];
}

// ---------------- row softmax: 2048 fp32 -> 2048 fp16, one block per row ----------------
__device__ __forceinline__ float wredmax(float v) {
#pragma unroll
    for (int off = 32; off > 0; off >>= 1) v = fmaxf(v, __shfl_xor(v, off, 64));
    return v;
}
__device__ __forceinline__ float wredsum(float v) {
#pragma unroll
    for (int off = 32; off > 0; off >>= 1) v += __shfl_xor(v, off, 64);
    return v;
}

__global__ __launch_bounds__(256) void k_softmax(const float* __restrict__ S,
                                                 _Float16* __restrict__ P) {
    __shared__ float red[8];
    size_t base = (size_t)blockIdx.x * 2048;
    int t = threadIdx.x;
    float4 a = ((const float4*)(S + base))[2 * t];
    float4 b = ((const float4*)(S + base))[2 * t + 1];
    float v[8] = {a.x, a.y, a.z, a.w, b.x, b.y, b.z, b.w};
    float m = v[0];
#pragma unroll
    for (int j = 1; j < 8; j++) m = fmaxf(m, v[j]);
    m = wredmax(m);
    int wv = t >> 6;
    if ((t & 63) == 0) red[wv] = m;
    __syncthreads();
    m = fmaxf(fmaxf(red[0], red[1]), fmaxf(red[2], red[3]));
    float s = 0.f;
#pragma unroll
    for (int j = 0; j < 8; j++) { v[j] = __expf(v[j] - m); s += v[j]; }
    s = wredsum(s);
    if ((t & 63) == 0) red[4 + wv] = s;
    __syncthreads();
    s = red[4] + red[5] + red[6] + red[7];
    float inv = 1.f / s;
    half4v o0, o1;
#pragma unroll
    for (int j = 0; j < 4; j++) o0[j] = (_Float16)(v[j] * inv);
#pragma unroll
    for (int j = 0; j < 4; j++) o1[j] = (_Float16)(v[4 + j] * inv);
    ((half4v*)(P + base))[2 * t] = o0;
    ((half4v*)(P + base))[2 * t + 1] = o1;
}

// ---------------- 128-tile fp16 GEMM (m97 structure, proven) ----------------
// OUT_MODE: 0=f32  4=fp16  5=fp16 transposed per 2048-row batch
template <int OUT_MODE, bool GELU_ACT>
__global__ __launch_bounds__(256, 2) void k_gemmh(
    const us* __restrict__ A, const us* __restrict__ B,
    const float* __restrict__ bias, void* __restrict__ C,
    int N, int K, long sA, long sB, long sC) {
    __shared__ __align__(16) us lds[2][4096];

    const int tid = threadIdx.x;
    const int wave = tid >> 6, lane = tid & 63;
    const int wr = wave >> 1, wc = wave & 1;
    const int l15 = lane & 15, l4 = lane >> 4;
    const int m0 = blockIdx.x * 128, n0 = blockIdx.y * 128;
    const us* pA = A + (size_t)blockIdx.z * sA;
    const us* pB = B + (size_t)blockIdx.z * sB;
    const size_t zC = (size_t)blockIdx.z * sC;

    f32x4 acc[4][4] = {};

    auto stage = [&](const us* __restrict__ g, us* l, int r0, int kk) {
#pragma unroll
        for (int i = 0; i < 2; i++) {
            int s = (i << 8) + tid;
            int row = s >> 2;
            int chunk = (s & 3) ^ ((row >> 1) & 3);
            const us* src = g + (size_t)(r0 + row) * K + kk + chunk * 8;
            us* dst = l + (((i << 8) + (wave << 6)) << 3);
            GLDS16(src, dst);
        }
    };

    for (int kk = 0; kk < K; kk += 32) {
        stage(pA, lds[0], m0, kk);
        stage(pB, lds[1], n0, kk);
        __syncthreads();

        short8 af[4], bf[4];
#pragma unroll
        for (int f = 0; f < 4; f++) {
            int ra = (wr << 6) + (f << 4) + l15;
            af[f] = *(const short8*)(&lds[0][(ra << 5) + ((l4 ^ ((ra >> 1) & 3)) << 3)]);
            int rb = (wc << 6) + (f << 4) + l15;
            bf[f] = *(const short8*)(&lds[1][(rb << 5) + ((l4 ^ ((rb >> 1) & 3)) << 3)]);
        }
#pragma unroll
        for (int fm = 0; fm < 4; fm++)
#pragma unroll
            for (int fn = 0; fn < 4; fn++)
                acc[fm][fn] = __builtin_amdgcn_mfma_f32_16x16x32_f16(
                    __builtin_bit_cast(half8, af[fm]), __builtin_bit_cast(half8, bf[fn]),
                    acc[fm][fn], 0, 0, 0);
        __syncthreads();
    }

    float bv[4];
#pragma unroll
    for (int fn = 0; fn < 4; fn++)
        bv[fn] = bias ? bias[n0 + (wc << 6) + (fn << 4) + l15] : 0.f;

#pragma unroll
    for (int fm = 0; fm < 4; fm++) {
        int rbase = m0 + (wr << 6) + (fm << 4) + (l4 << 2);
#pragma unroll
        for (int fn = 0; fn < 4; fn++) {
            int col = n0 + (wc << 6) + (fn << 4) + l15;
#pragma unroll
            for (int r = 0; r < 4; r++) {
                float x = acc[fm][fn][r] + bv[fn];
                if (GELU_ACT) x = 0.5f * x * (1.f + erff(x * 0.70710678118654752f));
                size_t row = (size_t)(rbase + r);
                if (OUT_MODE == 5) {
                    size_t o = ((row >> 11) * (size_t)N + (size_t)col) * 2048 + (row & 2047);
                    ((_Float16*)C)[o] = (_Float16)x;
                } else {
                    size_t o = zC + row * N + col;
                    if (OUT_MODE == 0) ((float*)C)[o] = x;
                    else               ((_Float16*)C)[o] = (_Float16)x;
                }
            }
        }
    }
}

// ---------------- 256-tile, BK=64, phase-pipelined fp16 GEMM ----------------
// 8 waves (2M x 4N), per-wave 128x64 out. LDS: A,B x 2 ping-pong buffers of
// [2 halves][128x64] = 128 KiB. Per K-tile: 4 phases x {ds_read 2 A-frags
// (+8 B-frags at q0, reg-resident per tile) | stage tile t+1 halves into the
// OTHER buffer (race-free: its readers finished at prior end-of-iter barrier)
// | barrier | setprio(1) 16 MFMA setprio(0) | barrier}. Single vmcnt(0) at q3:
// every load has >=1 phase (~620 cyc MFMA/SIMD) of cover. Swizzle: 16B chunk
// index ^= (row&7) within each 128B row, applied pre-swizzled on the global
// source + on ds_read addr (rule #21) -> 2-way bank access (free).
template <int OUT_MODE, bool GELU_ACT>
__global__ __launch_bounds__(512, 2) void k_gemmpp(
    const us* __restrict__ A, const us* __restrict__ B,
    const float* __restrict__ bias, void* __restrict__ C,
    int N, int K) {
    __shared__ __align__(16) us ldsA[2][2][8192];
    __shared__ __align__(16) us ldsB[2][2][8192];

    const int tid = threadIdx.x;
    const int wave = tid >> 6, lane = tid & 63;
    const int wr = wave >> 2, wc = wave & 3;  // 2M x 4N
    const int l15 = lane & 15, l4 = lane >> 4;
    const int m0 = blockIdx.x * 256, n0 = blockIdx.y * 256;
    const int NT = K >> 6;

    f32x4 acc[8][4] = {};

    // stage one 128x64 fp16 half-tile (16 KiB, 2 global_load_lds rounds)
    auto stageHalf = [&](const us* __restrict__ g, us* ldst, int grow0, int kk) {
#pragma unroll
        for (int j = 0; j < 2; ++j) {
            int s = (j << 9) + tid;              // 16B slot 0..1023
            int row = s >> 3;                    // 0..127
            int cl = (s & 7) ^ (row & 7);        // pre-swizzled logical chunk
            const us* src = g + (size_t)(grow0 + row) * K + kk + (cl << 3);
            us* dst = ldst + (((j << 9) + (wave << 6)) << 3);  // wave-uniform base
            GLDS16(src, dst);
        }
    };

    // prologue: stage tile 0 into buffer 0
    stageHalf(A, &ldsA[0][0][0], m0, 0);
    stageHalf(A, &ldsA[0][1][0], m0 + 128, 0);
    stageHalf(B, &ldsB[0][0][0], n0, 0);
    stageHalf(B, &ldsB[0][1][0], n0 + 128, 0);
    asm volatile("s_waitcnt vmcnt(0)" ::: "memory");
    __builtin_amdgcn_s_barrier();
    __builtin_amdgcn_sched_barrier(0);

    for (int t = 0; t < NT; ++t) {
        const int c = t & 1;
        const us* baA = &ldsA[c][wr][0];
        const us* baB = &ldsB[c][wc >> 1][0];
        const int kk1 = (t + 1) << 6;
        const bool pf = (t + 1 < NT);
        short8 bfrag[4][2];
#pragma unroll
        for (int q = 0; q < 4; ++q) {
            if (q == 0) {  // B fragments once per K-tile (8 x ds_read_b128)
#pragma unroll
                for (int fb = 0; fb < 4; ++fb) {
                    int row = ((wc & 1) << 6) + (fb << 4) + l15;
#pragma unroll
                    for (int ks = 0; ks < 2; ++ks)
                        bfrag[fb][ks] = *(const short8*)(
                            baB + row * 64 + ((((ks << 2) + l4) ^ (row & 7)) << 3));
                }
            }
            short8 afrag[2][2];  // this phase's 2 A-fragments (4 x ds_read_b128)
#pragma unroll
            for (int i = 0; i < 2; ++i) {
                int row = (((q << 1) + i) << 4) + l15;
#pragma unroll
                for (int ks = 0; ks < 2; ++ks)
                    afrag[i][ks] = *(const short8*)(
                        baA + row * 64 + ((((ks << 2) + l4) ^ (row & 7)) << 3));
            }
            if (pf) {  // stage tile t+1 into the other buffer
                if (q == 0) {
                    stageHalf(A, &ldsA[c ^ 1][0][0], m0, kk1);
                    stageHalf(A, &ldsA[c ^ 1][1][0], m0 + 128, kk1);
                } else if (q == 1) {
                    stageHalf(B, &ldsB[c ^ 1][0][0], n0, kk1);
                } else if (q == 2) {
                    stageHalf(B, &ldsB[c ^ 1][1][0], n0 + 128, kk1);
                }
            }
            __builtin_amdgcn_s_barrier();
            __builtin_amdgcn_s_setprio(1);
#pragma unroll
            for (int i = 0; i < 2; ++i)
#pragma unroll
                for (int fn = 0; fn < 4; ++fn)
#pragma unroll
                    for (int ks = 0; ks < 2; ++ks)
                        acc[(q << 1) + i][fn] = __builtin_amdgcn_mfma_f32_16x16x32_f16(
                            __builtin_bit_cast(half8, afrag[i][ks]),
                            __builtin_bit_cast(half8, bfrag[fn][ks]),
                            acc[(q << 1) + i][fn], 0, 0, 0);
            __builtin_amdgcn_s_setprio(0);
            if (q == 3 && pf)
                asm volatile("s_waitcnt vmcnt(0)" ::: "memory");
            __builtin_amdgcn_s_barrier();
            __builtin_amdgcn_sched_barrier(0);
        }
    }

    float bv[4];
#pragma unroll
    for (int fn = 0; fn < 4; ++fn)
        bv[fn] = bias ? bias[n0 + (wc << 6) + (fn << 4) + l15] : 0.f;
#pragma unroll
    for (int fm = 0; fm < 8; ++fm) {
        int rbase = m0 + (wr << 7) + (fm << 4) + (l4 << 2);
#pragma unroll
        for (int fn = 0; fn < 4; ++fn) {
            int col = n0 + (wc << 6) + (fn << 4) + l15;
#pragma unroll
            for (int r = 0; r < 4; ++r) {
                float x = acc[fm][fn][r] + bv[fn];
                if (GELU_ACT) x = 0.5f * x * (1.f + erff(x * 0.70710678118654752f));
                size_t row = (size_t)(rbase + r);
                size_t o = row * (size_t)N + col;
                if (OUT_MODE == 0) ((float*)C)[o] = x;
                else               ((_Float16*)C)[o] = (_Float16)x;
            }
        }
    }
}

extern "C" void kernel_launch(void* const* d_in, const int* in_sizes, int n_in,
                              void* d_out, int out_size, void* d_ws, size_t ws_size,
                              hipStream_t stream) {
    (void)in_sizes; (void)n_in; (void)out_size;
    const float* g_q   = (const float*)d_in[0];
    const float* g_kv  = (const float*)d_in[1];
    const float* g_Wkv = (const float*)d_in[2];
    const float* g_bkv = (const float*)d_in[3];
    const float* g_Wq  = (const float*)d_in[4];
    const float* g_bq  = (const float*)d_in[5];
    const float* g_W1  = (const float*)d_in[6];
    const float* g_b1  = (const float*)d_in[7];
    const float* g_W2  = (const float*)d_in[8];
    const float* g_b2  = (const float*)d_in[9];

    const size_t MiB = 1048576ull;
    const long SH = 2048L * 1024;
    const long SS = 2048L * 2048;
    char* ws = (char*)d_ws;
    dim3 tb32(32, 8);

    if (ws_size < 176 * MiB) {
        k_sentinel<<<1, 64, 0, stream>>>((float*)d_out);
        return;
    }

    // ---- workspace layout (176 MiB) ----
    _Float16* xq  = (_Float16*)ws;
    char*     BIG = ws + 32 * MiB;
    _Float16* xkv = (_Float16*)BIG;
    _Float16* kf  = (_Float16*)(BIG + 33554432);
    _Float16* vT  = (_Float16*)(BIG + 67108864);
    _Float16* hidden = (_Float16*)BIG;            // 16384x4096 fp16 = 128 MiB exact
    char* wreg = ws + 160 * MiB;
    _Float16* WkvT = (_Float16*)wreg;
    _Float16* WqT  = (_Float16*)(wreg + 4194304);
    _Float16* W1T  = (_Float16*)wreg;             // overlays proj weights (dead by MLP)
    _Float16* W2T  = (_Float16*)(wreg + 8388608);

    float*    scores_c = (float*)d_out;
    _Float16* P_c  = (_Float16*)((char*)d_out + 33554432);
    _Float16* q_c  = (_Float16*)((char*)d_out + 50331648);

    // ---- weights + input casts ----
    k_wtransh<<<dim3(64, 32), tb32, 0, stream>>>(g_Wkv, WkvT, 1024, 2048);
    k_wtransh<<<dim3(32, 32), tb32, 0, stream>>>(g_Wq, WqT, 1024, 1024);
    k_cast<<<4096, 256, 0, stream>>>(g_kv, xkv, 4194304);
    k_cast<<<4096, 256, 0, stream>>>(g_q, xq, 4194304);

    // ---- projections (128-tile kernel, proven) ----
    k_gemmh<4, false><<<dim3(128, 8, 1), 256, 0, stream>>>(
        (const us*)xkv, (const us*)WkvT, g_bkv, kf, 1024, 1024, 0, 0, 0);
    k_gemmh<5, false><<<dim3(128, 8, 1), 256, 0, stream>>>(
        (const us*)xkv, (const us*)(WkvT + (size_t)1024 * 1024), g_bkv + 1024, vT,
        1024, 1024, 0, 0, 0);

    // ---- attention, 4 chunks of 2 batches ----
    for (int c = 0; c < 4; ++c) {
        size_t ro = (size_t)c * 4096 * 1024;
        k_gemmh<4, false><<<dim3(32, 8, 1), 256, 0, stream>>>(
            (const us*)(xq + ro), (const us*)WqT, g_bq, q_c, 1024, 1024, 0, 0, 0);
        k_gemmh<0, false><<<dim3(16, 16, 2), 256, 0, stream>>>(
            (const us*)q_c, (const us*)(kf + ro), nullptr, scores_c,
            2048, 1024, SH, SH, SS);
        k_softmax<<<4096, 256, 0, stream>>>(scores_c, P_c);
        k_gemmh<4, false><<<dim3(16, 8, 2), 256, 0, stream>>>(
            (const us*)P_c, (const us*)(vT + ro), nullptr, xq + ro,
            1024, 2048, SS, SH, SH);
    }

    // ---- MLP on the new 256-tile pipelined kernel (within-round A/B vs k_gemmh) ----
    k_wtransh<<<dim3(128, 32), tb32, 0, stream>>>(g_W1, W1T, 1024, 4096);
    k_wtransh<<<dim3(32, 128), tb32, 0, stream>>>(g_W2, W2T, 4096, 1024);
    k_gemmpp<4, true><<<dim3(64, 16), 512, 0, stream>>>(
        (const us*)xq, (const us*)W1T, g_b1, hidden, 4096, 1024);
    k_gemmpp<0, false><<<dim3(64, 4), 512, 0, stream>>>(
        (const us*)hidden, (const us*)W2T, g_b2, d_out, 1024, 4096);
}

// Round 6
// 817.613 us; speedup vs baseline: 1.5636x; 1.1178x over previous
//
#include <hip/hip_runtime.h>
#include <hip/hip_bf16.h>

typedef __attribute__((ext_vector_type(8))) short short8;
typedef __attribute__((ext_vector_type(8))) _Float16 half8;
typedef __attribute__((ext_vector_type(4))) _Float16 half4v;
typedef __attribute__((ext_vector_type(4))) float f32x4;
typedef unsigned short us;

#define GLDS16(G, L) __builtin_amdgcn_global_load_lds( \
    (const __attribute__((address_space(1))) void*)(G), \
    (__attribute__((address_space(3))) void*)(L), 16, 0, 0)

__global__ void k_sentinel(float* p) {
    if (threadIdx.x == 0 && blockIdx.x == 0) p[0] = 12345.0f;
}

// ---------------- cast fp32 -> fp16 ----------------
__global__ void k_cast(const float* __restrict__ in, _Float16* __restrict__ out, long n4) {
    long i = (long)blockIdx.x * blockDim.x + threadIdx.x;
    long stride = (long)gridDim.x * blockDim.x;
    for (; i < n4; i += stride) {
        float4 v = ((const float4*)in)[i];
        half4v h;
        h[0] = (_Float16)v.x; h[1] = (_Float16)v.y;
        h[2] = (_Float16)v.z; h[3] = (_Float16)v.w;
        ((half4v*)out)[i] = h;
    }
}

// ---------------- weight transpose+cast: f32 [K][N] -> fp16 [N][K] ----------------
__global__ void k_wtransh(const float* __restrict__ in, _Float16* __restrict__ out,
                          int K, int N) {
    __shared__ float tile[32][33];
    int n0 = blockIdx.x * 32, k0 = blockIdx.y * 32;
    int tx = threadIdx.x, ty = threadIdx.y;
#pragma unroll
    for (int r = ty; r < 32; r += 8)
        tile[r][tx] = in[(size_t)(k0 + r) * N + n0 + tx];
    __syncthreads();
#pragma unroll
    for (int r = ty; r < 32; r += 8)
        out[(size_t)(n0 + r) * K + k0 + tx] = (_Float16)tile[tx][r];
}

// ---------------- row softmax: 2048 fp32 -> 2048 fp16, one block per row ----------------
__device__ __forceinline__ float wredmax(float v) {
#pragma unroll
    for (int off = 32; off > 0; off >>= 1) v = fmaxf(v, __shfl_xor(v, off, 64));
    return v;
}
__device__ __forceinline__ float wredsum(float v) {
#pragma unroll
    for (int off = 32; off > 0; off >>= 1) v += __shfl_xor(v, off, 64);
    return v;
}

__global__ __launch_bounds__(256) void k_softmax(const float* __restrict__ S,
                                                 _Float16* __restrict__ P) {
    __shared__ float red[8];
    size_t base = (size_t)blockIdx.x * 2048;
    int t = threadIdx.x;
    float4 a = ((const float4*)(S + base))[2 * t];
    float4 b = ((const float4*)(S + base))[2 * t + 1];
    float v[8] = {a.x, a.y, a.z, a.w, b.x, b.y, b.z, b.w};
    float m = v[0];
#pragma unroll
    for (int j = 1; j < 8; j++) m = fmaxf(m, v[j]);
    m = wredmax(m);
    int wv = t >> 6;
    if ((t & 63) == 0) red[wv] = m;
    __syncthreads();
    m = fmaxf(fmaxf(red[0], red[1]), fmaxf(red[2], red[3]));
    float s = 0.f;
#pragma unroll
    for (int j = 0; j < 8; j++) { v[j] = __expf(v[j] - m); s += v[j]; }
    s = wredsum(s);
    if ((t & 63) == 0) red[4 + wv] = s;
    __syncthreads();
    s = red[4] + red[5] + red[6] + red[7];
    float inv = 1.f / s;
    half4v o0, o1;
#pragma unroll
    for (int j = 0; j < 4; j++) o0[j] = (_Float16)(v[j] * inv);
#pragma unroll
    for (int j = 0; j < 4; j++) o1[j] = (_Float16)(v[4 + j] * inv);
    ((half4v*)(P + base))[2 * t] = o0;
    ((half4v*)(P + base))[2 * t + 1] = o1;
}

// ---------------- 128-tile fp16 GEMM (m97 structure, proven) ----------------
// OUT_MODE: 0=f32  4=fp16  5=fp16 transposed per 2048-row batch
template <int OUT_MODE, bool GELU_ACT>
__global__ __launch_bounds__(256, 2) void k_gemmh(
    const us* __restrict__ A, const us* __restrict__ B,
    const float* __restrict__ bias, void* __restrict__ C,
    int N, int K, long sA, long sB, long sC) {
    __shared__ __align__(16) us lds[2][4096];

    const int tid = threadIdx.x;
    const int wave = tid >> 6, lane = tid & 63;
    const int wr = wave >> 1, wc = wave & 1;
    const int l15 = lane & 15, l4 = lane >> 4;
    const int m0 = blockIdx.x * 128, n0 = blockIdx.y * 128;
    const us* pA = A + (size_t)blockIdx.z * sA;
    const us* pB = B + (size_t)blockIdx.z * sB;
    const size_t zC = (size_t)blockIdx.z * sC;

    f32x4 acc[4][4] = {};

    auto stage = [&](const us* __restrict__ g, us* l, int r0, int kk) {
#pragma unroll
        for (int i = 0; i < 2; i++) {
            int s = (i << 8) + tid;
            int row = s >> 2;
            int chunk = (s & 3) ^ ((row >> 1) & 3);
            const us* src = g + (size_t)(r0 + row) * K + kk + chunk * 8;
            us* dst = l + (((i << 8) + (wave << 6)) << 3);
            GLDS16(src, dst);
        }
    };

    for (int kk = 0; kk < K; kk += 32) {
        stage(pA, lds[0], m0, kk);
        stage(pB, lds[1], n0, kk);
        __syncthreads();

        short8 af[4], bf[4];
#pragma unroll
        for (int f = 0; f < 4; f++) {
            int ra = (wr << 6) + (f << 4) + l15;
            af[f] = *(const short8*)(&lds[0][(ra << 5) + ((l4 ^ ((ra >> 1) & 3)) << 3)]);
            int rb = (wc << 6) + (f << 4) + l15;
            bf[f] = *(const short8*)(&lds[1][(rb << 5) + ((l4 ^ ((rb >> 1) & 3)) << 3)]);
        }
#pragma unroll
        for (int fm = 0; fm < 4; fm++)
#pragma unroll
            for (int fn = 0; fn < 4; fn++)
                acc[fm][fn] = __builtin_amdgcn_mfma_f32_16x16x32_f16(
                    __builtin_bit_cast(half8, af[fm]), __builtin_bit_cast(half8, bf[fn]),
                    acc[fm][fn], 0, 0, 0);
        __syncthreads();
    }

    float bv[4];
#pragma unroll
    for (int fn = 0; fn < 4; fn++)
        bv[fn] = bias ? bias[n0 + (wc << 6) + (fn << 4) + l15] : 0.f;

#pragma unroll
    for (int fm = 0; fm < 4; fm++) {
        int rbase = m0 + (wr << 6) + (fm << 4) + (l4 << 2);
#pragma unroll
        for (int fn = 0; fn < 4; fn++) {
            int col = n0 + (wc << 6) + (fn << 4) + l15;
#pragma unroll
            for (int r = 0; r < 4; r++) {
                float x = acc[fm][fn][r] + bv[fn];
                if (GELU_ACT) x = 0.5f * x * (1.f + erff(x * 0.70710678118654752f));
                size_t row = (size_t)(rbase + r);
                if (OUT_MODE == 5) {
                    size_t o = ((row >> 11) * (size_t)N + (size_t)col) * 2048 + (row & 2047);
                    ((_Float16*)C)[o] = (_Float16)x;
                } else {
                    size_t o = zC + row * N + col;
                    if (OUT_MODE == 0) ((float*)C)[o] = x;
                    else               ((_Float16*)C)[o] = (_Float16)x;
                }
            }
        }
    }
}

extern "C" void kernel_launch(void* const* d_in, const int* in_sizes, int n_in,
                              void* d_out, int out_size, void* d_ws, size_t ws_size,
                              hipStream_t stream) {
    (void)in_sizes; (void)n_in; (void)out_size;
    const float* g_q   = (const float*)d_in[0];
    const float* g_kv  = (const float*)d_in[1];
    const float* g_Wkv = (const float*)d_in[2];
    const float* g_bkv = (const float*)d_in[3];
    const float* g_Wq  = (const float*)d_in[4];
    const float* g_bq  = (const float*)d_in[5];
    const float* g_W1  = (const float*)d_in[6];
    const float* g_b1  = (const float*)d_in[7];
    const float* g_W2  = (const float*)d_in[8];
    const float* g_b2  = (const float*)d_in[9];

    const size_t MiB = 1048576ull;
    const long SH = 2048L * 1024;   // per-batch activation elements
    const long SS = 2048L * 2048;   // per-batch score elements
    char* ws = (char*)d_ws;
    dim3 tb32(32, 8);

    if (ws_size < 176 * MiB) {
        k_sentinel<<<1, 64, 0, stream>>>((float*)d_out);
        return;
    }

    // ---- workspace layout (176 MiB) ----
    // [xq/attnout 32][REGION 128: attn {kf 32 | vT 32 | P_all 64}, MLP hidden 128][wreg 16]
    _Float16* xq  = (_Float16*)ws;
    char*     REGION = ws + 32 * MiB;
    _Float16* kf    = (_Float16*)REGION;
    _Float16* vT    = (_Float16*)(REGION + 32 * MiB);
    _Float16* P_all = (_Float16*)(REGION + 64 * MiB);   // 8 x 2048 x 2048 fp16 = 64 MiB
    _Float16* hidden = (_Float16*)REGION;               // 16384 x 4096 fp16 = 128 MiB
    char* wreg = ws + 160 * MiB;
    _Float16* WkvT = (_Float16*)wreg;                   // 4 MiB
    _Float16* WqT  = (_Float16*)(wreg + 4 * MiB);       // 2 MiB
    _Float16* W1T  = (_Float16*)wreg;                   // 8 MiB (overlays, proj weights dead)
    _Float16* W2T  = (_Float16*)(wreg + 8 * MiB);       // 8 MiB

    // d_out (64+ MiB) as scratch: [xkv 32 | ...] during proj, [scores 32 | q_all 32] in attn
    _Float16* xkv      = (_Float16*)d_out;
    float*    scores_c = (float*)d_out;                       // 2-batch fp32 scores, 32 MiB
    _Float16* q_all    = (_Float16*)((char*)d_out + 32 * MiB); // 32 MiB

    // ---- weights + input casts ----
    k_wtransh<<<dim3(64, 32), tb32, 0, stream>>>(g_Wkv, WkvT, 1024, 2048);
    k_wtransh<<<dim3(32, 32), tb32, 0, stream>>>(g_Wq, WqT, 1024, 1024);
    k_cast<<<4096, 256, 0, stream>>>(g_kv, xkv, 4194304);
    k_cast<<<4096, 256, 0, stream>>>(g_q, xq, 4194304);

    // ---- projections (full-width dispatches, 4 blocks/CU) ----
    k_gemmh<4, false><<<dim3(128, 8, 1), 256, 0, stream>>>(
        (const us*)xkv, (const us*)WkvT, g_bkv, kf, 1024, 1024, 0, 0, 0);
    k_gemmh<5, false><<<dim3(128, 8, 1), 256, 0, stream>>>(
        (const us*)xkv, (const us*)(WkvT + (size_t)1024 * 1024), g_bkv + 1024, vT,
        1024, 1024, 0, 0, 0);
    // q-projection for ALL batches in one dispatch (xkv dead; q_all in d_out upper half)
    k_gemmh<4, false><<<dim3(128, 8, 1), 256, 0, stream>>>(
        (const us*)xq, (const us*)WqT, g_bq, q_all, 1024, 1024, 0, 0, 0);

    // ---- scores + softmax in 4 chunks of 2 batches (scores in d_out lower half) ----
    for (int c = 0; c < 4; ++c) {
        size_t ro = (size_t)c * 4096 * 1024;
        k_gemmh<0, false><<<dim3(16, 16, 2), 256, 0, stream>>>(
            (const us*)(q_all + ro), (const us*)(kf + ro), nullptr, scores_c,
            2048, 1024, SH, SH, SS);
        k_softmax<<<4096, 256, 0, stream>>>(scores_c, P_all + (size_t)c * 2 * SS);
    }

    // ---- PV for ALL batches in one dispatch (1024 blocks, 4/CU); overwrite xq ----
    k_gemmh<4, false><<<dim3(16, 8, 8), 256, 0, stream>>>(
        (const us*)P_all, (const us*)vT, nullptr, xq, 1024, 2048, SS, SH, SH);

    // ---- MLP (hidden overlays REGION; kf/vT/P_all dead) ----
    k_wtransh<<<dim3(128, 32), tb32, 0, stream>>>(g_W1, W1T, 1024, 4096);
    k_wtransh<<<dim3(32, 128), tb32, 0, stream>>>(g_W2, W2T, 4096, 1024);
    k_gemmh<4, true><<<dim3(128, 32, 1), 256, 0, stream>>>(
        (const us*)xq, (const us*)W1T, g_b1, hidden, 4096, 1024, 0, 0, 0);
    k_gemmh<0, false><<<dim3(128, 8, 1), 256, 0, stream>>>(
        (const us*)hidden, (const us*)W2T, g_b2, d_out, 1024, 4096, 0, 0, 0);
}